// Round 13
// baseline (53.965 us; speedup 1.0000x reference)
//
#include <hip/hip_runtime.h>

// SSIM loss, 7x7 window, VALID, (64,1,512,512) fp32.
// R13: 2 output cols/lane, incremental horizontal 7-tap (col B = col A
// - tap0 + tap7), 4 vertical channels (sx, sy, sxy, ss=sxx+syy), LDS as
// interleaved {x,y} float2 per col -> 4x ds_read_b128 + 1x ds_write_b128
// per row-iter per 2 cols (was 7x b64 + 2 writes per 1 col). Barrier-free
// wave-private strips, depth-2 prefetch, fast rcp, no launch_bounds pin.

constexpr int B  = 64;
constexpr int H  = 512, W = 512;
constexpr int OH = H - 6, OW = W - 6;     // 506
constexpr int SH = 32;                    // output rows per block

__global__ __launch_bounds__(256)
void ssim_main(const float* __restrict__ X, const float* __restrict__ Y,
               const float* __restrict__ DR, float* __restrict__ partials)
{
    const int tid  = threadIdx.x;
    const int wid  = tid >> 6;
    const int lane = tid & 63;
    const int c0   = wid * 128;             // wave col base; block spans 512
    const int r0   = blockIdx.y * SH;
    const int b    = blockIdx.z;

    const int out_rows = min(SH, OH - r0);
    const int rows_in  = out_rows + 6;      // <= 38

    const float d  = DR[b];
    const float C1 = (0.01f * d) * (0.01f * d);
    const float C2 = (0.03f * d) * (0.03f * d);
    const float c1s = 2401.0f * C1;         // 49^2 * C1
    const float c2s = 2352.0f * C2;         // 48*49 * C2

    const float* __restrict__ Xb = X + (size_t)b * H * W;
    const float* __restrict__ Yb = Y + (size_t)b * H * W;

    const int cA = c0 + 2 * lane;           // owned col A (even)
    unsigned off  = (unsigned)(r0 * W + cA);
    unsigned hoff = (unsigned)(r0 * W + min(c0 + 128 + 2 * lane, W - 2));
    const bool vA = cA     < OW;
    const bool vB = cA + 1 < OW;
    const bool is_halo = lane < 3;          // halo cols c0+128..c0+133

    // per-wave row: 64 owned float4 slots {xA,yA,xB,yB} + 3 halo slots
    __shared__ float4 rb4[4][68];
    float4* const wrow = rb4[wid];
    const float4* const bp = &rb4[wid][lane];

    // vertical state: 4 channels x 2 cols; history 4ch x 7 x 2
    float vx0=0.f,vy0=0.f,vxy0=0.f,vss0=0.f;
    float vx1=0.f,vy1=0.f,vxy1=0.f,vss1=0.f;
    float bhx0[7],bhy0[7],bhxy0[7],bhss0[7];
    float bhx1[7],bhy1[7],bhxy1[7],bhss1[7];
#pragma unroll
    for (int i = 0; i < 7; ++i) {
        bhx0[i]=bhy0[i]=bhxy0[i]=bhss0[i]=0.f;
        bhx1[i]=bhy1[i]=bhxy1[i]=bhss1[i]=0.f;
    }

    float acc = 0.f;

    // depth-2 prefetch
    float2 px0, py0, px1, py1;
    float2 phx0 = make_float2(0.f,0.f), phy0 = phx0, phx1 = phx0, phy1 = phx0;
    px0 = *(const float2*)(Xb + off);  py0 = *(const float2*)(Yb + off);
    if (is_halo) { phx0 = *(const float2*)(Xb + hoff); phy0 = *(const float2*)(Yb + hoff); }
    off += W; hoff += W;
    px1 = *(const float2*)(Xb + off);  py1 = *(const float2*)(Yb + off);
    if (is_halo) { phx1 = *(const float2*)(Xb + hoff); phy1 = *(const float2*)(Yb + hoff); }
    off += W; hoff += W;

    for (int rr = 0; rr < 42; rr += 14) {
#pragma unroll
        for (int p = 0; p < 14; ++p) {
            const int r = rr + p;            // r%7 == p%7, r&1 == p&1
            if (r < rows_in) {               // block-uniform
                float2& px = (p & 1) ? px1 : px0;
                float2& py = (p & 1) ? py1 : py0;
                float2& phx = (p & 1) ? phx1 : phx0;
                float2& phy = (p & 1) ? phy1 : phy0;

                wrow[lane] = make_float4(px.x, py.x, px.y, py.y);
                if (is_halo) wrow[64 + lane] = make_float4(phx.x, phy.x, phx.y, phy.y);
                // no barrier: wave-private region, DS ops in-order per wave

                // issue row r+2's loads; latency hides under compute
                if (r + 2 < rows_in) {
                    px = *(const float2*)(Xb + off);
                    py = *(const float2*)(Yb + off);
                    if (is_halo) {
                        phx = *(const float2*)(Xb + hoff);
                        phy = *(const float2*)(Yb + hoff);
                    }
                    off += W; hoff += W;
                }

                // 8 input cols (2i..2i+7) as 4 x b128
                const float4 q0 = bp[0], q1 = bp[1], q2 = bp[2], q3 = bp[3];
                const float x0=q0.x,y0=q0.y,x1=q0.z,y1=q0.w;
                const float x2=q1.x,y2=q1.y,x3=q1.z,y3=q1.w;
                const float x4=q2.x,y4=q2.y,x5=q2.z,y5=q2.w;
                const float x6=q3.x,y6=q3.y,x7=q3.z,y7=q3.w;

                // horizontal sums, col A = taps 0..6
                const float hxA = ((x0+x1)+(x2+x3)) + ((x4+x5)+x6);
                const float hyA = ((y0+y1)+(y2+y3)) + ((y4+y5)+y6);
                const float xy0 = x0*y0;
                const float hxyA = fmaf(x6,y6, fmaf(x5,y5, fmaf(x4,y4,
                                   fmaf(x3,y3, fmaf(x2,y2, fmaf(x1,y1, xy0))))));
                const float ss0 = fmaf(x0,x0, y0*y0);
                const float hssA = fmaf(y6,y6, fmaf(x6,x6, fmaf(y5,y5, fmaf(x5,x5,
                                   fmaf(y4,y4, fmaf(x4,x4, fmaf(y3,y3, fmaf(x3,x3,
                                   fmaf(y2,y2, fmaf(x2,x2, fmaf(y1,y1, fmaf(x1,x1, ss0))))))))))));
                // col B = col A - tap0 + tap7
                const float hxB  = (hxA - x0) + x7;
                const float hyB  = (hyA - y0) + y7;
                const float hxyB = fmaf(x7,y7, hxyA - xy0);
                const float ss7  = fmaf(x7,x7, y7*y7);
                const float hssB = (hssA - ss0) + ss7;

                // vertical running 7-row window (slot p%7 holds row r-7)
                constexpr int s7[14] = {0,1,2,3,4,5,6,0,1,2,3,4,5,6};
                const int sp = s7[p];
                vx0  += hxA  - bhx0[sp];  bhx0[sp]  = hxA;
                vy0  += hyA  - bhy0[sp];  bhy0[sp]  = hyA;
                vxy0 += hxyA - bhxy0[sp]; bhxy0[sp] = hxyA;
                vss0 += hssA - bhss0[sp]; bhss0[sp] = hssA;
                vx1  += hxB  - bhx1[sp];  bhx1[sp]  = hxB;
                vy1  += hyB  - bhy1[sp];  bhy1[sp]  = hyB;
                vxy1 += hxyB - bhxy1[sp]; bhxy1[sp] = hxyB;
                vss1 += hssB - bhss1[sp]; bhss1[sp] = hssB;

                if (r >= 6) {
                    // S = (2 sx sy + c1s)(2(49 sxy - sx sy) + c2s)
                    //   / (sx^2+sy^2+c1s)(49 ss - sx^2 - sy^2 + c2s)
                    {   const float p1 = vx0 * vy0;
                        const float t1 = fmaf(2.f, p1, c1s);
                        const float qq = fmaf(49.f, vxy0, -p1);
                        const float t2 = fmaf(2.f, qq, c2s);
                        const float n2 = fmaf(vy0, vy0, vx0*vx0);
                        const float b1 = n2 + c1s;
                        const float b2 = fmaf(49.f, vss0, c2s) - n2;
                        const float den = b1 * b2;
                        float rc = __builtin_amdgcn_rcpf(den);
                        rc = rc * (2.f - den * rc);
                        const float sA = (t1 * t2) * rc;
                        acc += vA ? sA : 0.f;
                    }
                    {   const float p1 = vx1 * vy1;
                        const float t1 = fmaf(2.f, p1, c1s);
                        const float qq = fmaf(49.f, vxy1, -p1);
                        const float t2 = fmaf(2.f, qq, c2s);
                        const float n2 = fmaf(vy1, vy1, vx1*vx1);
                        const float b1 = n2 + c1s;
                        const float b2 = fmaf(49.f, vss1, c2s) - n2;
                        const float den = b1 * b2;
                        float rc = __builtin_amdgcn_rcpf(den);
                        rc = rc * (2.f - den * rc);
                        const float sB = (t1 * t2) * rc;
                        acc += vB ? sB : 0.f;
                    }
                }
            }
        }
    }

    // block reduction: wave shfl, then cross-wave via LDS (single barrier)
    float s = acc;
#pragma unroll
    for (int o = 32; o; o >>= 1) s += __shfl_down(s, o, 64);
    __shared__ float wsum[4];
    if (lane == 0) wsum[wid] = s;
    __syncthreads();
    if (tid == 0) {
        const int bid = blockIdx.z * gridDim.y + blockIdx.y;
        partials[bid] = wsum[0] + wsum[1] + wsum[2] + wsum[3];
    }
}

__global__ __launch_bounds__(256)
void ssim_final(const float* __restrict__ partials, int n,
                float* __restrict__ out, float inv_count)
{
    const int tid = threadIdx.x;
    float s = 0.f;
    for (int i = tid; i < n; i += 256) s += partials[i];
#pragma unroll
    for (int o = 32; o; o >>= 1) s += __shfl_down(s, o, 64);
    __shared__ float wsum[4];
    if ((tid & 63) == 0) wsum[tid >> 6] = s;
    __syncthreads();
    if (tid == 0) out[0] = 1.0f - (wsum[0] + wsum[1] + wsum[2] + wsum[3]) * inv_count;
}

extern "C" void kernel_launch(void* const* d_in, const int* in_sizes, int n_in,
                              void* d_out, int out_size, void* d_ws, size_t ws_size,
                              hipStream_t stream)
{
    const float* X  = (const float*)d_in[0];
    const float* Y  = (const float*)d_in[1];
    const float* DR = (const float*)d_in[2];
    float* out      = (float*)d_out;
    float* partials = (float*)d_ws;

    const int gy = (OH + SH - 1) / SH;   // 16
    dim3 grid(1, gy, B);                 // 1024 blocks, every partial slot written
    ssim_main<<<grid, 256, 0, stream>>>(X, Y, DR, partials);

    const int n = gy * B;                // 1024
    const float inv_count = 1.0f / (float)((long)B * OH * OW);
    ssim_final<<<1, 256, 0, stream>>>(partials, n, out, inv_count);
}

// Round 14
// 47.693 us; speedup vs baseline: 1.1315x; 1.1315x over previous
//
#include <hip/hip_runtime.h>

// SSIM loss, 7x7 window, VALID, (64,1,512,512) fp32.
// R14 = R12 structure (1 col/lane, 5ch, 7x ds_read_b64, VGPR=40) with
// SH 64->32: 2048 blocks = 8 blocks/CU = 32 waves/CU (full slot count).
// R12's pipes ran in SUM (VALU 31us + LDS 26us ~= 55us) due to 16-wave
// residency; doubling occupancy should overlap them toward max().
// R13's 2-col/lane retired: VGPR 84 halved occupancy, net loss.

constexpr int B  = 64;
constexpr int H  = 512, W = 512;
constexpr int OH = H - 6, OW = W - 6;     // 506
constexpr int CW = 64;                    // output cols per wave
constexpr int BW_ = 4 * CW;               // output cols per block (256)
constexpr int SH = 32;                    // output rows per block

__global__ __launch_bounds__(256)
void ssim_main(const float* __restrict__ X, const float* __restrict__ Y,
               const float* __restrict__ DR, float* __restrict__ partials)
{
    const int tid  = threadIdx.x;
    const int wid  = tid >> 6;
    const int lane = tid & 63;
    const int c0   = blockIdx.x * BW_ + wid * CW;   // wave-private strip
    const int r0   = blockIdx.y * SH;
    const int b    = blockIdx.z;

    const int out_rows = min(SH, OH - r0);
    const int rows_in  = out_rows + 6;       // <= 38

    const float d  = DR[b];
    const float C1 = (0.01f * d) * (0.01f * d);
    const float C2 = (0.03f * d) * (0.03f * d);
    const float c1s = 2401.0f * C1;          // 49^2 * C1
    const float c2s = 2352.0f * C2;          // 48*49 * C2

    const float* __restrict__ Xb = X + (size_t)b * H * W;
    const float* __restrict__ Yb = Y + (size_t)b * H * W;

    // 32-bit offsets, one increment per row; halo address clamped in-bounds
    // (clamped values only ever feed invalid outputs)
    unsigned off  = (unsigned)(r0 * W + c0 + lane);
    unsigned hoff = (unsigned)(r0 * W + min(c0 + CW + lane, W - 1));

    const bool colvalid = (c0 + lane) < OW;
    const bool is_halo  = lane < 6;

    // wave-private single row buffer: {x,y} pairs, 70 used
    __shared__ float2 rb[4][CW + 8];
    float2* const buf = rb[wid];

    // vertical circular buffers (statically indexed via unroll)
    float bx[7], by[7], bxx[7], byy[7], bxy[7];
    float vsx = 0.f, vsy = 0.f, vsxx = 0.f, vsyy = 0.f, vsxy = 0.f;
#pragma unroll
    for (int i = 0; i < 7; ++i) { bx[i]=by[i]=bxx[i]=byy[i]=bxy[i]=0.f; }

    float acc = 0.f;

    // depth-2 prefetch: pre0/preh0 = even rows, pre1/preh1 = odd rows
    float2 pre0, pre1;
    float2 preh0 = make_float2(0.f, 0.f), preh1 = make_float2(0.f, 0.f);
    pre0.x = Xb[off]; pre0.y = Yb[off];
    if (is_halo) { preh0.x = Xb[hoff]; preh0.y = Yb[hoff]; }
    off += W; hoff += W;
    pre1.x = Xb[off]; pre1.y = Yb[off];
    if (is_halo) { preh1.x = Xb[hoff]; preh1.y = Yb[hoff]; }
    off += W; hoff += W;

    for (int rr = 0; rr < 42; rr += 14) {
#pragma unroll
        for (int p = 0; p < 14; ++p) {
            const int r = rr + p;              // r%7 == p%7, r&1 == p&1
            if (r < rows_in) {                 // block-uniform
                float2& pr = (p & 1) ? pre1 : pre0;
                float2& ph = (p & 1) ? preh1 : preh0;
                buf[lane] = pr;
                if (is_halo) buf[CW + lane] = ph;
                // no barrier: wave-private region, DS ops in order per wave

                // issue row r+2's loads now; 2 iterations of latency cover
                if (r + 2 < rows_in) {
                    pr.x = Xb[off]; pr.y = Yb[off];
                    if (is_halo) { ph.x = Xb[hoff]; ph.y = Yb[hoff]; }
                    off += W; hoff += W;
                }

                // horizontal 7-tap sums of the 5 channels
                float hx = 0.f, hy = 0.f, hxx = 0.f, hyy = 0.f, hxy = 0.f;
#pragma unroll
                for (int i = 0; i < 7; ++i) {
                    const float2 v = buf[lane + i];
                    hx += v.x; hy += v.y;
                    hxx = fmaf(v.x, v.x, hxx);
                    hyy = fmaf(v.y, v.y, hyy);
                    hxy = fmaf(v.x, v.y, hxy);
                }

                // vertical running 7-row window (slot p%7 holds row r-7)
                constexpr int s7[14] = {0,1,2,3,4,5,6,0,1,2,3,4,5,6};
                const int sp = s7[p];
                vsx  += hx  - bx[sp];  bx[sp]  = hx;
                vsy  += hy  - by[sp];  by[sp]  = hy;
                vsxx += hxx - bxx[sp]; bxx[sp] = hxx;
                vsyy += hyy - byy[sp]; byy[sp] = hyy;
                vsxy += hxy - bxy[sp]; bxy[sp] = hxy;

                if (r >= 6 && colvalid) {
                    // normalization-cancelled SSIM on raw sums:
                    // S = (2 sx sy + c1s)(2(49 sxy - sx sy) + c2s)
                    //   / (sx^2+sy^2+c1s)(49(sxx+syy) - sx^2 - sy^2 + c2s)
                    const float p1 = vsx * vsy;
                    const float t1 = fmaf(2.f, p1, c1s);
                    const float q  = fmaf(49.f, vsxy, -p1);
                    const float t2 = fmaf(2.f, q, c2s);
                    const float n1 = vsx * vsx;
                    const float n2 = fmaf(vsy, vsy, n1);
                    const float b1 = n2 + c1s;
                    const float s3 = vsxx + vsyy;
                    const float b2 = fmaf(49.f, s3, c2s) - n2;
                    const float num = t1 * t2;
                    const float den = b1 * b2;
                    float rcp = __builtin_amdgcn_rcpf(den);
                    rcp = rcp * (2.f - den * rcp);      // 1 Newton step
                    acc = fmaf(num, rcp, acc);
                }
            }
        }
    }

    // block reduction: wave shfl, then cross-wave via LDS (single barrier)
    float s = acc;
#pragma unroll
    for (int offr = 32; offr; offr >>= 1) s += __shfl_down(s, offr, 64);
    __shared__ float wsum[4];
    if (lane == 0) wsum[wid] = s;
    __syncthreads();
    if (tid == 0) {
        const int bid = (blockIdx.z * gridDim.y + blockIdx.y) * gridDim.x + blockIdx.x;
        partials[bid] = wsum[0] + wsum[1] + wsum[2] + wsum[3];
    }
}

__global__ __launch_bounds__(256)
void ssim_final(const float* __restrict__ partials, int n,
                float* __restrict__ out, float inv_count)
{
    const int tid = threadIdx.x;
    float s = 0.f;
    for (int i = tid; i < n; i += 256) s += partials[i];
#pragma unroll
    for (int off = 32; off; off >>= 1) s += __shfl_down(s, off, 64);
    __shared__ float wsum[4];
    if ((tid & 63) == 0) wsum[tid >> 6] = s;
    __syncthreads();
    if (tid == 0) out[0] = 1.0f - (wsum[0] + wsum[1] + wsum[2] + wsum[3]) * inv_count;
}

extern "C" void kernel_launch(void* const* d_in, const int* in_sizes, int n_in,
                              void* d_out, int out_size, void* d_ws, size_t ws_size,
                              hipStream_t stream)
{
    const float* X  = (const float*)d_in[0];
    const float* Y  = (const float*)d_in[1];
    const float* DR = (const float*)d_in[2];
    float* out      = (float*)d_out;
    float* partials = (float*)d_ws;

    const int gx = (OW + BW_ - 1) / BW_; // 2
    const int gy = (OH + SH - 1) / SH;   // 16
    dim3 grid(gx, gy, B);                // 2048 blocks, every partial slot written
    ssim_main<<<grid, 256, 0, stream>>>(X, Y, DR, partials);

    const int n = gx * gy * B;           // 2048
    const float inv_count = 1.0f / (float)((long)B * OH * OW);
    ssim_final<<<1, 256, 0, stream>>>(partials, n, out, inv_count);
}